// Round 16
// baseline (188.910 us; speedup 1.0000x reference)
//
#include <hip/hip_runtime.h>
#include <hip/hip_bf16.h>

typedef __bf16 bf16x8 __attribute__((ext_vector_type(8)));
typedef float  f32x4  __attribute__((ext_vector_type(4)));

// float -> bf16 round-to-nearest-even (finite inputs)
__device__ __forceinline__ unsigned short f2bf(float f) {
    union { float f; unsigned int u; } v; v.f = f;
    unsigned int r = v.u + 0x7FFFu + ((v.u >> 16) & 1u);
    return (unsigned short)(r >> 16);
}

__device__ __forceinline__ void async16(const unsigned short* g, unsigned short* l) {
    __builtin_amdgcn_global_load_lds(
        (const __attribute__((address_space(1))) unsigned int*)g,
        (__attribute__((address_space(3))) unsigned int*)l,
        16, 0, 0);
}

// ---------------------------------------------------------------------------
// Transpose + cast + even/odd row pack: Xt[n][pi(m)] = (bf16) X[m][n]
// ---------------------------------------------------------------------------
__global__ __launch_bounds__(256) void transpose_perm(
    const float* __restrict__ X, unsigned short* __restrict__ Xt, int Mr, int Nc)
{
    __shared__ float tile[64][65];
    const int bx = blockIdx.x * 64;   // n base
    const int by = blockIdx.y * 64;   // m base
    const int tid = threadIdx.x;
    const int halfM = Mr >> 1;

    const int c4 = (tid & 15) * 4;
    const int r  = tid >> 4;
#pragma unroll
    for (int p = 0; p < 4; ++p) {
        const float4 v = *reinterpret_cast<const float4*>(
            &X[(size_t)(by + r + 16 * p) * Nc + bx + c4]);
        tile[r + 16 * p][c4 + 0] = v.x;
        tile[r + 16 * p][c4 + 1] = v.y;
        tile[r + 16 * p][c4 + 2] = v.z;
        tile[r + 16 * p][c4 + 3] = v.w;
    }
    __syncthreads();

    const int q  = tid & 7;
    const int h  = (tid >> 3) & 1;
    const int n0 = tid >> 4;
#pragma unroll
    for (int p = 0; p < 4; ++p) {
        const int n = n0 + 16 * p;
        ushort4 o;
        o.x = f2bf(tile[8 * q + 0 + h][n]);
        o.y = f2bf(tile[8 * q + 2 + h][n]);
        o.z = f2bf(tile[8 * q + 4 + h][n]);
        o.w = f2bf(tile[8 * q + 6 + h][n]);
        *reinterpret_cast<ushort4*>(
            Xt + (size_t)(bx + n) * Mr + h * halfM + (by >> 1) + 4 * q) = o;
    }
}

// ---------------------------------------------------------------------------
// Generate packed half-transform matrix W [2048][4096]:
//   col < 2048: kk = 2*col (even);  col >= 2048: kk = 2*(col-2048)+1 (odd)
//   W[r][col] = sin(pi*kk*(2r+1)/8192) (doSin) else cos(...)
// ---------------------------------------------------------------------------
__global__ __launch_bounds__(256) void gen_w(
    unsigned short* __restrict__ out, int doSin)
{
    const int flat = (int)(((size_t)blockIdx.x * 256 + threadIdx.x) * 4);
    const int r  = flat >> 12;
    const int c0 = flat & 4095;
    const unsigned int step = 2u * (unsigned int)r + 1u;
    const float scale = 3.14159265358979323846f / 8192.0f;
    unsigned short o[4];
#pragma unroll
    for (int j = 0; j < 4; ++j) {
        const int c = c0 + j;
        const unsigned int kk = (c < 2048) ? (unsigned int)(2 * c)
                                           : (unsigned int)(2 * (c - 2048) + 1);
        unsigned int p = (kk * step) & 16383u;
        float ang = (float)p * scale;
        float v = doSin ? __sinf(ang) : __cosf(ang);
        o[j] = f2bf(v);
    }
    uint2 pack;
    pack.x = (unsigned int)o[0] | ((unsigned int)o[1] << 16);
    pack.y = (unsigned int)o[2] | ((unsigned int)o[3] << 16);
    *reinterpret_cast<uint2*>(out + flat) = pack;
}

// ---------------------------------------------------------------------------
// Fused dual-pass BT-GEMM + butterfly epilogue, register-prefetch pipeline.
//   pass0: accE[i][j] = sum_{k<2048} P[i][k]      Q[j][k]
//   pass1: accO[i][j] = sum_{k<2048} P[i][2048+k] Q[j][2048+k]
// EPI=1 (stage1, ushort): C[i][pi(j)] = E+O ; C[4095-i][pi(j)] = O-E
// EPI=2 (stage2, float) : C[i][j]     = E+O ; C[i][4095-j]     = E-O
// Tile BM=BMU*64 x BN=BNU*64 (BMU+BNU=6), 8 waves of 64x64, BK=64.
// LDS: 3-buffer ring x 48 KB = 144 KiB. Per tile t:
//   LD F_next(t+1 frags, from lb_nxt) | STAGE data(t+3) -> lb_cur
//   MFMA F_cur (no wait: regs) | LGKM0 | VM6 | BARRIER | rotate ring.
// vmcnt(6) at tile end drains stage(t-1) = data(t+1) BEFORE the barrier, so
// every wave's prefetch at t+1 sees landed data. WAR on lb_cur: its frags
// were read at t-1, drained by t-1's LGKM0+barrier.
// ---------------------------------------------------------------------------
#define BARRIER __builtin_amdgcn_s_barrier()
#define LGKM0 asm volatile("s_waitcnt lgkmcnt(0)" ::: "memory")
#define VM6 asm volatile("s_waitcnt vmcnt(6)" ::: "memory")
#define VM0 asm volatile("s_waitcnt vmcnt(0)" ::: "memory")
#define PRIO1 __builtin_amdgcn_s_setprio(1)
#define PRIO0 __builtin_amdgcn_s_setprio(0)

#define STAGE_ALL(LB, KC) do { \
    _Pragma("unroll") for (int U = 0; U < BMU; ++U) \
        async16(pA + (size_t)U * 64 * 4096 + (KC), &lds[(LB) + U * 4096 + ldst]); \
    _Pragma("unroll") for (int U = 0; U < BNU; ++U) \
        async16(pB + (size_t)U * 64 * 4096 + (KC), &lds[(LB) + (BMU + U) * 4096 + ldst]); } while (0)

#define LDF(AF, BF, LB) do { \
    _Pragma("unroll") for (int mm = 0; mm < 4; ++mm) { \
        AF[mm][0] = *(const bf16x8*)&lds[(LB) + aOff + mm * 1024 + sl0]; \
        AF[mm][1] = *(const bf16x8*)&lds[(LB) + aOff + mm * 1024 + sl1]; } \
    _Pragma("unroll") for (int nn = 0; nn < 4; ++nn) { \
        BF[nn][0] = *(const bf16x8*)&lds[(LB) + bOff + nn * 1024 + sl0]; \
        BF[nn][1] = *(const bf16x8*)&lds[(LB) + bOff + nn * 1024 + sl1]; } } while (0)

#define MFMAF(AF, BF, ACC) do { \
    _Pragma("unroll") for (int ks = 0; ks < 2; ++ks) \
    _Pragma("unroll") for (int mm = 0; mm < 4; ++mm) \
    _Pragma("unroll") for (int nn = 0; nn < 4; ++nn) \
        ACC[mm][nn] = __builtin_amdgcn_mfma_f32_16x16x32_bf16( \
            AF[mm][ks], BF[nn][ks], ACC[mm][nn], 0, 0, 0); } while (0)

#define ROTATE do { const int _t = lb_cur; lb_cur = lb_nxt; lb_nxt = lb_n2; lb_n2 = _t; } while (0)

// one pipelined tile: prefetch (FA_N,FB_N), stage tile TTS, compute (FA_C,FB_C)
#define TILE_PF(FA_N, FB_N, FA_C, FB_C, ACC, TTS, DOSTG, VMW) do { \
    LDF(FA_N, FB_N, lb_nxt); \
    if (DOSTG) { const int _kc = (((TTS) >> 5) << 11) + (((TTS) & 31) << 6); \
                 STAGE_ALL(lb_cur, _kc); } \
    PRIO1; MFMAF(FA_C, FB_C, ACC); PRIO0; \
    LGKM0; VMW; BARRIER; \
    ROTATE; } while (0)

template <int BMU, int BNU, int EPI, typename OutT>
__global__ __launch_bounds__(512, 2) void gemm_fused(
    const unsigned short* __restrict__ P,
    const unsigned short* __restrict__ Q,
    OutT* __restrict__ C)
{
    __shared__ __align__(16) unsigned short lds[3 * 6 * 4096];

    const int tid  = threadIdx.x;
    const int lane = tid & 63;
    const int w    = tid >> 6;
    const int wm   = w / BNU;
    const int wn   = w % BNU;

    // XCD-bijective swizzle over 256 blocks; 16x16 tile grid
    const int bid = blockIdx.x;
    const int wg  = (bid & 7) * 32 + (bid >> 3);
    const int brow = (wg >> 4) * (BMU * 64);
    const int bcol = (wg & 15) * (BNU * 64);

    // staging: thread -> (64-row unit row, 16B slot), source col pre-swizzled
    const int srow = tid >> 3;
    const int sxor = ((tid & 7) ^ (srow & 7)) << 3;
    const unsigned short* pA = P + (size_t)(brow + srow) * 4096 + sxor;
    const unsigned short* pB = Q + (size_t)(bcol + srow) * 4096 + sxor;
    const int ldst = w << 9;     // wave-uniform LDS dest (+lane*16B by HW)

    // fragment-read constants (read-side swizzle matches source XOR)
    const int lr = lane & 15, lk = lane >> 4, sx = lr & 7;
    const int sl0 = ((lk) ^ sx) << 3;
    const int sl1 = ((4 + lk) ^ sx) << 3;
    const int aOff = (wm * 64 + lr) * 64;
    const int bOff = BMU * 4096 + (wn * 64 + lr) * 64;

    bf16x8 af0[4][2], bf0[4][2];   // fragment set 0 (even tiles)
    bf16x8 af1[4][2], bf1[4][2];   // fragment set 1 (odd tiles)
    f32x4 accE[4][4] = {};
    f32x4 accO[4][4] = {};

    // prologue: tiles 0,1,2 -> ring buffers 0,1,2; tiles 0+1 landed; F0 <- tile0
    STAGE_ALL(0, 0);
    STAGE_ALL(24576, 64);
    STAGE_ALL(49152, 128);
    VM6;          // 18 outstanding -> 6: tiles 0,1 landed (tile2 in flight)
    BARRIER;
    LDF(af0, bf0, 0);
    LGKM0;        // all waves' tile-0 frag reads done before t=0 stages into buf0
    BARRIER;

    int lb_cur = 0, lb_nxt = 24576, lb_n2 = 49152;

    // pass E: tiles 0..31 (stage tts = 3..34)
    for (int p = 0; p < 16; ++p) {
        TILE_PF(af1, bf1, af0, bf0, accE, 2 * p + 3, 1, VM6);
        TILE_PF(af0, bf0, af1, bf1, accE, 2 * p + 4, 1, VM6);
    }
    // pass O: tiles 32..59 (stage tts = 35..62)
    for (int p = 0; p < 14; ++p) {
        TILE_PF(af1, bf1, af0, bf0, accO, 2 * p + 35, 1, VM6);
        TILE_PF(af0, bf0, af1, bf1, accO, 2 * p + 36, 1, VM6);
    }
    // t=60: stage data(63); t=61: drain staging; t=62/63: pure compute
    TILE_PF(af1, bf1, af0, bf0, accO, 63, 1, VM6);
    TILE_PF(af0, bf0, af1, bf1, accO, 0, 0, VM0);
    LDF(af1, bf1, lb_nxt);
    PRIO1; MFMAF(af0, bf0, accO); PRIO0;
    LGKM0;
    PRIO1; MFMAF(af1, bf1, accO); PRIO0;

    // fused butterfly epilogue. frag: row=(lane>>4)*4+r, col=lane&15
    const int r0 = brow + wm * 64 + (lane >> 4) * 4;
    const int c0 = bcol + wn * 64 + (lane & 15);
#pragma unroll
    for (int mf = 0; mf < 4; ++mf)
#pragma unroll
        for (int nf = 0; nf < 4; ++nf)
#pragma unroll
            for (int r = 0; r < 4; ++r) {
                const int row = r0 + mf * 16 + r;
                const int col = c0 + nf * 16;
                const float e = accE[mf][nf][r];
                const float o = accO[mf][nf][r];
                if (EPI == 1) {
                    // T[u][pi(n)] = E+O ; T[4095-u][pi(n)] = O-E   (bf16)
                    const int pin = (col >> 1) + ((col & 1) << 11);
                    ((unsigned short*)C)[(size_t)row * 4096 + pin] = f2bf(e + o);
                    ((unsigned short*)C)[(size_t)(4095 - row) * 4096 + pin] = f2bf(o - e);
                } else {
                    // out[u][v] = E+O ; out[u][4095-v] = E-O        (f32)
                    ((float*)C)[(size_t)row * 4096 + col] = e + o;
                    ((float*)C)[(size_t)row * 4096 + 4095 - col] = e - o;
                }
            }
}

// ---------------------------------------------------------------------------
// launch:
//   Xt = X^T (bf16, even/odd m packed)          -> R0
//   W1 = [sin_e | sin_o]                        -> R1
//   T  = fused(IDXST stage + butterfly)          -> R2   (pi-packed n cols)
//   W2 = [cos_e | cos_o]                        -> R1
//   out = fused(IDCT stage + butterfly)          -> d_out (f32)
// ws: R0 32MB | R1 16MB | R2 32MB = 80MB
// ---------------------------------------------------------------------------
extern "C" void kernel_launch(void* const* d_in, const int* in_sizes, int n_in,
                              void* d_out, int out_size, void* d_ws, size_t ws_size,
                              hipStream_t stream) {
    const float* X = (const float*)d_in[0];
    const int Mr = in_sizes[1] / 2;   // 4096
    const int Nc = in_sizes[2] / 2;   // 4096

    unsigned short* R0 = (unsigned short*)d_ws;          // Xt [4096][4096]
    unsigned short* R1 = R0 + (size_t)Mr * Nc;           // W  [2048][4096]
    unsigned short* R2 = R1 + (size_t)(Mr / 2) * Nc;     // T  [4096][4096]

    transpose_perm<<<dim3(Nc / 64, Mr / 64), 256, 0, stream>>>(X, R0, Mr, Nc);
    gen_w<<<(2048 * 4096 / 4) / 256, 256, 0, stream>>>(R1, 1);
    gemm_fused<2, 4, 1, unsigned short><<<256, 512, 0, stream>>>(R1, R0, R2);
    gen_w<<<(2048 * 4096 / 4) / 256, 256, 0, stream>>>(R1, 0);
    gemm_fused<4, 2, 2, float><<<256, 512, 0, stream>>>(R2, R1, (float*)d_out);
}

// Round 17
// 167.827 us; speedup vs baseline: 1.1256x; 1.1256x over previous
//
#include <hip/hip_runtime.h>
#include <hip/hip_bf16.h>

typedef __bf16 bf16x8 __attribute__((ext_vector_type(8)));
typedef float  f32x4  __attribute__((ext_vector_type(4)));

// float -> bf16 round-to-nearest-even (finite inputs)
__device__ __forceinline__ unsigned short f2bf(float f) {
    union { float f; unsigned int u; } v; v.f = f;
    unsigned int r = v.u + 0x7FFFu + ((v.u >> 16) & 1u);
    return (unsigned short)(r >> 16);
}

__device__ __forceinline__ void async16(const unsigned short* g, unsigned short* l) {
    __builtin_amdgcn_global_load_lds(
        (const __attribute__((address_space(1))) unsigned int*)g,
        (__attribute__((address_space(3))) unsigned int*)l,
        16, 0, 0);
}

// ---------------------------------------------------------------------------
// Transpose + cast + even/odd row pack: Xt[n][pi(m)] = (bf16) X[m][n]
// ---------------------------------------------------------------------------
__global__ __launch_bounds__(256) void transpose_perm(
    const float* __restrict__ X, unsigned short* __restrict__ Xt, int Mr, int Nc)
{
    __shared__ float tile[64][65];
    const int bx = blockIdx.x * 64;   // n base
    const int by = blockIdx.y * 64;   // m base
    const int tid = threadIdx.x;
    const int halfM = Mr >> 1;

    const int c4 = (tid & 15) * 4;
    const int r  = tid >> 4;
#pragma unroll
    for (int p = 0; p < 4; ++p) {
        const float4 v = *reinterpret_cast<const float4*>(
            &X[(size_t)(by + r + 16 * p) * Nc + bx + c4]);
        tile[r + 16 * p][c4 + 0] = v.x;
        tile[r + 16 * p][c4 + 1] = v.y;
        tile[r + 16 * p][c4 + 2] = v.z;
        tile[r + 16 * p][c4 + 3] = v.w;
    }
    __syncthreads();

    const int q  = tid & 7;
    const int h  = (tid >> 3) & 1;
    const int n0 = tid >> 4;
#pragma unroll
    for (int p = 0; p < 4; ++p) {
        const int n = n0 + 16 * p;
        ushort4 o;
        o.x = f2bf(tile[8 * q + 0 + h][n]);
        o.y = f2bf(tile[8 * q + 2 + h][n]);
        o.z = f2bf(tile[8 * q + 4 + h][n]);
        o.w = f2bf(tile[8 * q + 6 + h][n]);
        *reinterpret_cast<ushort4*>(
            Xt + (size_t)(bx + n) * Mr + h * halfM + (by >> 1) + 4 * q) = o;
    }
}

// ---------------------------------------------------------------------------
// Generate packed half-transform matrix W [2048][4096]:
//   col < 2048: kk = 2*col (even);  col >= 2048: kk = 2*(col-2048)+1 (odd)
//   W[r][col] = sin(pi*kk*(2r+1)/8192) (doSin) else cos(...)
// ---------------------------------------------------------------------------
__global__ __launch_bounds__(256) void gen_w(
    unsigned short* __restrict__ out, int doSin)
{
    const int flat = (int)(((size_t)blockIdx.x * 256 + threadIdx.x) * 4);
    const int r  = flat >> 12;
    const int c0 = flat & 4095;
    const unsigned int step = 2u * (unsigned int)r + 1u;
    const float scale = 3.14159265358979323846f / 8192.0f;
    unsigned short o[4];
#pragma unroll
    for (int j = 0; j < 4; ++j) {
        const int c = c0 + j;
        const unsigned int kk = (c < 2048) ? (unsigned int)(2 * c)
                                           : (unsigned int)(2 * (c - 2048) + 1);
        unsigned int p = (kk * step) & 16383u;
        float ang = (float)p * scale;
        float v = doSin ? __sinf(ang) : __cosf(ang);
        o[j] = f2bf(v);
    }
    uint2 pack;
    pack.x = (unsigned int)o[0] | ((unsigned int)o[1] << 16);
    pack.y = (unsigned int)o[2] | ((unsigned int)o[3] << 16);
    *reinterpret_cast<uint2*>(out + flat) = pack;
}

// ---------------------------------------------------------------------------
// Fused dual-pass BT-GEMM + butterfly epilogue — 128x128 tile, 2 blocks/CU.
//   accE[i][j] = sum_{k<2048} P[i][k]      Q[j][k]   (tiles 0..31)
//   accO[i][j] = sum_{k<2048} P[i][2048+k] Q[j][2048+k] (tiles 32..63)
// EPI=1 (stage1, ushort): C[i][pi(j)] = E+O ; C[4095-i][pi(j)] = O-E
// EPI=2 (stage2, float) : C[i][j]     = E+O ; C[i][4095-j]     = E-O
// 4 waves (2Mx2N) of 64x64; BK=64; LDS ring-2 x 32KB = 64 KiB -> 2 blocks/CU.
// Per tile t: STAGE(t+1 -> other buf, issued FIRST) | LD_ALL(cur) | MFMA |
//   LGKM0 | VM0 | BARRIER.  VM0 waits only this tile's 8 stage ops, issued a
//   full tile earlier. Cross-block overlap (m114) hides the stalls.
// ---------------------------------------------------------------------------
#define BARRIER __builtin_amdgcn_s_barrier()
#define LGKM0 asm volatile("s_waitcnt lgkmcnt(0)" ::: "memory")
#define VM0 asm volatile("s_waitcnt vmcnt(0)" ::: "memory")
#define PRIO1 __builtin_amdgcn_s_setprio(1)
#define PRIO0 __builtin_amdgcn_s_setprio(0)

#define STAGE(LB, KC) do { \
    _Pragma("unroll") for (int p = 0; p < 8; ++p) \
        async16(srcp_[p] + (KC), &lds[(LB) + ((p * 256 + wbase) * 8)]); } while (0)

#define LD_ALL(LB) do { \
    _Pragma("unroll") for (int mm = 0; mm < 4; ++mm) { \
        af[mm][0] = *(const bf16x8*)&lds[(LB) + aOff + mm * 1024 + sl0]; \
        af[mm][1] = *(const bf16x8*)&lds[(LB) + aOff + mm * 1024 + sl1]; } \
    _Pragma("unroll") for (int nn = 0; nn < 4; ++nn) { \
        bfr[nn][0] = *(const bf16x8*)&lds[(LB) + bOff + nn * 1024 + sl0]; \
        bfr[nn][1] = *(const bf16x8*)&lds[(LB) + bOff + nn * 1024 + sl1]; } } while (0)

#define MFMA_ALL(ACC) do { \
    _Pragma("unroll") for (int ks = 0; ks < 2; ++ks) \
    _Pragma("unroll") for (int mm = 0; mm < 4; ++mm) \
    _Pragma("unroll") for (int nn = 0; nn < 4; ++nn) \
        ACC[mm][nn] = __builtin_amdgcn_mfma_f32_16x16x32_bf16( \
            af[mm][ks], bfr[nn][ks], ACC[mm][nn], 0, 0, 0); } while (0)

template <int EPI, typename OutT>
__global__ __launch_bounds__(256, 2) void gemm_fused(
    const unsigned short* __restrict__ P,
    const unsigned short* __restrict__ Q,
    OutT* __restrict__ C, int nbx)
{
    __shared__ __align__(16) unsigned short lds[2 * 4 * 4096];   // 64 KiB

    const int tid  = threadIdx.x;
    const int lane = tid & 63;
    const int w    = tid >> 6;       // 0..3
    const int wm   = w >> 1;
    const int wn   = w & 1;

    // XCD-bijective swizzle over 512 blocks
    const int bid = blockIdx.x;
    const int wg  = (bid & 7) * (gridDim.x >> 3) + (bid >> 3);
    const int brow = (wg / nbx) * 128;
    const int bcol = (wg % nbx) * 128;

    // staging: 8 chunks/thread; chunk c = p*256 + tid; unit c>>9 (A0,A1,B0,B1),
    // row (c>>3)&63, 16B slot c&7; source col pre-swizzled (XOR row&7).
    const unsigned short* srcp_[8];
    const int wbase = tid & ~63;     // wave-uniform chunk base component
#pragma unroll
    for (int p = 0; p < 8; ++p) {
        const int c    = p * 256 + tid;
        const int unit = c >> 9;
        const int urow = (c >> 3) & 63;
        const int slot = c & 7;
        const int sx   = (slot ^ (urow & 7)) << 3;
        srcp_[p] = (unit < 2)
            ? P + (size_t)(brow + unit * 64 + urow) * 4096 + sx
            : Q + (size_t)(bcol + (unit - 2) * 64 + urow) * 4096 + sx;
    }

    // fragment-read constants (read-side swizzle matches source XOR)
    const int lr = lane & 15, lk = lane >> 4, sx = lr & 7;
    const int sl0 = ((lk) ^ sx) << 3;
    const int sl1 = ((4 + lk) ^ sx) << 3;
    const int aOff = wm * 4096 + lr * 64;          // A units 0,1
    const int bOff = (2 + wn) * 4096 + lr * 64;    // B units 2,3

    bf16x8 af[4][2], bfr[4][2];
    f32x4 accE[4][4] = {};
    f32x4 accO[4][4] = {};

    // prologue: tile 0 -> buf 0
    STAGE(0, 0);
    VM0;
    BARRIER;

    // pass E: tiles 0..31 (kc = t*64)
    for (int t = 0; t < 32; ++t) {
        const int lb = (t & 1) << 14;
        const int nb = lb ^ 16384;
        STAGE(nb, (t + 1) << 6);
        LD_ALL(lb);
        PRIO1; MFMA_ALL(accE); PRIO0;
        LGKM0; VM0; BARRIER;
    }
    // pass O: tiles 32..62
    for (int t = 32; t < 63; ++t) {
        const int lb = (t & 1) << 14;
        const int nb = lb ^ 16384;
        STAGE(nb, (t + 1) << 6);
        LD_ALL(lb);
        PRIO1; MFMA_ALL(accO); PRIO0;
        LGKM0; VM0; BARRIER;
    }
    // tile 63: pure compute
    {
        const int lb = (63 & 1) << 14;
        LD_ALL(lb);
        PRIO1; MFMA_ALL(accO); PRIO0;
    }

    // fused butterfly epilogue. frag: row=(lane>>4)*4+r, col=lane&15
    const int r0 = brow + wm * 64 + (lane >> 4) * 4;
    const int c0 = bcol + wn * 64 + (lane & 15);
#pragma unroll
    for (int mf = 0; mf < 4; ++mf)
#pragma unroll
        for (int nf = 0; nf < 4; ++nf)
#pragma unroll
            for (int r = 0; r < 4; ++r) {
                const int row = r0 + mf * 16 + r;
                const int col = c0 + nf * 16;
                const float e = accE[mf][nf][r];
                const float o = accO[mf][nf][r];
                if (EPI == 1) {
                    // T[u][pi(n)] = E+O ; T[4095-u][pi(n)] = O-E   (bf16)
                    const int pin = (col >> 1) + ((col & 1) << 11);
                    ((unsigned short*)C)[(size_t)row * 4096 + pin] = f2bf(e + o);
                    ((unsigned short*)C)[(size_t)(4095 - row) * 4096 + pin] = f2bf(o - e);
                } else {
                    // out[u][v] = E+O ; out[u][4095-v] = E-O        (f32)
                    ((float*)C)[(size_t)row * 4096 + col] = e + o;
                    ((float*)C)[(size_t)row * 4096 + 4095 - col] = e - o;
                }
            }
}

// ---------------------------------------------------------------------------
// launch:
//   Xt = X^T (bf16, even/odd m packed)          -> R0
//   W1 = [sin_e | sin_o]                        -> R1
//   T  = fused(IDXST stage + butterfly)          -> R2   (pi-packed n cols)
//   W2 = [cos_e | cos_o]                        -> R1
//   out = fused(IDCT stage + butterfly)          -> d_out (f32)
// ws: R0 32MB | R1 16MB | R2 32MB = 80MB
// ---------------------------------------------------------------------------
extern "C" void kernel_launch(void* const* d_in, const int* in_sizes, int n_in,
                              void* d_out, int out_size, void* d_ws, size_t ws_size,
                              hipStream_t stream) {
    const float* X = (const float*)d_in[0];
    const int Mr = in_sizes[1] / 2;   // 4096
    const int Nc = in_sizes[2] / 2;   // 4096

    unsigned short* R0 = (unsigned short*)d_ws;          // Xt [4096][4096]
    unsigned short* R1 = R0 + (size_t)Mr * Nc;           // W  [2048][4096]
    unsigned short* R2 = R1 + (size_t)(Mr / 2) * Nc;     // T  [4096][4096]

    transpose_perm<<<dim3(Nc / 64, Mr / 64), 256, 0, stream>>>(X, R0, Mr, Nc);
    gen_w<<<(2048 * 4096 / 4) / 256, 256, 0, stream>>>(R1, 1);
    // stage1: output rows 0..2047, cols 0..4095 -> grid 16x32 = 512 blocks
    gemm_fused<1, unsigned short><<<512, 256, 0, stream>>>(R1, R0, R2, 32);
    gen_w<<<(2048 * 4096 / 4) / 256, 256, 0, stream>>>(R1, 0);
    // stage2: output rows 0..4095, cols 0..2047 -> grid 32x16 = 512 blocks
    gemm_fused<2, float><<<512, 256, 0, stream>>>(R2, R1, (float*)d_out, 16);
}